// Round 8
// baseline (211.892 us; speedup 1.0000x reference)
//
#include <hip/hip_runtime.h>
#include <cstdint>

typedef unsigned short u16;
typedef unsigned int u32;
typedef __attribute__((ext_vector_type(8))) short bf16x8;
typedef __attribute__((ext_vector_type(4))) short bf16x4;
typedef __attribute__((ext_vector_type(4))) float f32x4;

__device__ __forceinline__ float bf2f(short h) {
  union { u32 u; float f; } x; x.u = ((u32)(u16)h) << 16; return x.f;
}
__device__ __forceinline__ short f2bf(float f) {
  union { float f; u32 u; } x; x.f = f;
  u32 r = x.u + 0x7fffu + ((x.u >> 16) & 1u);
  return (short)(u16)(r >> 16);
}

// async global->LDS, 16B per lane; LDS dest is wave-uniform base + lane*16
__device__ __forceinline__ void gload16(const void* g, void* l) {
  __builtin_amdgcn_global_load_lds(
      (const __attribute__((address_space(1))) u32*)g,
      (__attribute__((address_space(3))) u32*)l, 16, 0, 0);
}

#define WAITV(N) asm volatile("s_waitcnt vmcnt(" #N ")" ::: "memory")
#define BARRIER() do { asm volatile("" ::: "memory"); \
  __builtin_amdgcn_s_barrier(); asm volatile("" ::: "memory"); } while (0)

// ---------------------------------------------------------------------------
// cast fp32 -> bf16, 8 elems/thread
// ---------------------------------------------------------------------------
__global__ __launch_bounds__(256) void cast_k(const float* __restrict__ in,
                                              u16* __restrict__ out) {
  int i = blockIdx.x * 256 + threadIdx.x;
  const float4* p = (const float4*)(in + (size_t)i * 8);
  float4 a = p[0], b = p[1];
  bf16x8 v;
  v[0] = f2bf(a.x); v[1] = f2bf(a.y); v[2] = f2bf(a.z); v[3] = f2bf(a.w);
  v[4] = f2bf(b.x); v[5] = f2bf(b.y); v[6] = f2bf(b.z); v[7] = f2bf(b.w);
  *(bf16x8*)(out + (size_t)i * 8) = v;
}

// ---------------------------------------------------------------------------
// cast+transpose all 4 weights: W fp32 [1024 k][1024 n] -> Wt bf16 [n][k]
// ---------------------------------------------------------------------------
__global__ __launch_bounds__(256) void castT4_k(
    const float* __restrict__ W0, const float* __restrict__ W1,
    const float* __restrict__ W2, const float* __restrict__ W3,
    u16* __restrict__ O0, u16* __restrict__ O1,
    u16* __restrict__ O2, u16* __restrict__ O3) {
  __shared__ u16 Ts[64 * 72];
  const int z = blockIdx.z;
  const float* in = z == 0 ? W0 : (z == 1 ? W1 : (z == 2 ? W2 : W3));
  u16* out = z == 0 ? O0 : (z == 1 ? O1 : (z == 2 ? O2 : O3));
  const int k0 = blockIdx.x * 64, n0 = blockIdx.y * 64;
  const int t = threadIdx.x;
  const int kr = t >> 4, nc = (t & 15) * 4;
#pragma unroll
  for (int p = 0; p < 4; ++p) {
    float4 v = *(const float4*)(in + (size_t)(k0 + kr + p * 16) * 1024 + n0 + nc);
    int kk = kr + p * 16;
    Ts[(nc + 0) * 72 + kk] = (u16)f2bf(v.x);
    Ts[(nc + 1) * 72 + kk] = (u16)f2bf(v.y);
    Ts[(nc + 2) * 72 + kk] = (u16)f2bf(v.z);
    Ts[(nc + 3) * 72 + kk] = (u16)f2bf(v.w);
  }
  __syncthreads();
  const int nr = t >> 2, kc = (t & 3) * 16;
  bf16x8 o0, o1;
#pragma unroll
  for (int j = 0; j < 8; ++j) {
    o0[j] = (short)Ts[nr * 72 + kc + j];
    o1[j] = (short)Ts[nr * 72 + kc + 8 + j];
  }
  *(bf16x8*)(out + (size_t)(n0 + nr) * 1024 + k0 + kc) = o0;
  *(bf16x8*)(out + (size_t)(n0 + nr) * 1024 + k0 + kc + 8) = o1;
}

// ---------------------------------------------------------------------------
// NT GEMM body, counted-vmcnt double-buffered pipeline.
// C[m][n] = sum_k A[m][k]*Bt[n][k], K=1024; BM=128, BN=NJ*32, BK=64, 4 waves.
// Per iter: issue next tile's global_load_lds (4+NJ per wave), wait vmcnt
// down to those (current tile done), raw barrier, MFMA, raw barrier.
// Prefetch loads stay in flight across the barrier (no vmcnt(0) drain).
// ---------------------------------------------------------------------------
template <int OUT_BF16, int NJ>
__device__ __forceinline__ void gemm_body(char* gsm, const u16* __restrict__ A,
                                          const u16* __restrict__ Bt,
                                          void* __restrict__ Cv,
                                          int row0, int col0) {
  constexpr int SB = 16384 + NJ * 4096;   // per-buffer bytes (A 16K | B NJ*4K)
  const int t = threadIdx.x;
  const int l = t & 63, w = t >> 6;
  const int lq = l & 15, g = l >> 4;
  const int wr = w >> 1, wc = w & 1;
  const int r8 = t >> 3;                       // staging row (0..31)
  const int c8 = (((t & 7) ^ (r8 & 7)) << 3);  // pre-swizzled col (elements)

  f32x4 acc[4][NJ] = {};

  auto stage = [&](int cb, int k0) {
    char* dst = gsm + cb * SB + w * 1024;
#pragma unroll
    for (int p = 0; p < 4; ++p)
      gload16(A + (size_t)(row0 + r8 + 32 * p) * 1024 + k0 + c8, dst + p * 4096);
#pragma unroll
    for (int p = 0; p < NJ; ++p)
      gload16(Bt + (size_t)(col0 + r8 + 32 * p) * 1024 + k0 + c8,
              dst + 16384 + p * 4096);
  };

  stage(0, 0);
  int cur = 0;
  for (int k0 = 0; k0 < 1024; k0 += 64) {
    if (k0 + 64 < 1024) {
      stage(cur ^ 1, k0 + 64);
      if constexpr (NJ == 4) WAITV(8); else WAITV(6);
    } else {
      WAITV(0);
    }
    BARRIER();
    __builtin_amdgcn_sched_barrier(0);
    const char* Ab = gsm + cur * SB;
#pragma unroll
    for (int ks = 0; ks < 2; ++ks) {
      bf16x8 af[4], bfr[NJ];
      const int sA = ks * 4 + g;
#pragma unroll
      for (int i = 0; i < 4; ++i) {
        int ra = wr * 64 + i * 16 + lq;
        af[i] = *(const bf16x8*)(Ab + ra * 128 + ((sA ^ (ra & 7)) << 4));
      }
#pragma unroll
      for (int j = 0; j < NJ; ++j) {
        int rb = wc * (NJ * 16) + j * 16 + lq;
        bfr[j] = *(const bf16x8*)(Ab + 16384 + rb * 128 + ((sA ^ (rb & 7)) << 4));
      }
#pragma unroll
      for (int i = 0; i < 4; ++i)
#pragma unroll
        for (int j = 0; j < NJ; ++j)
          acc[i][j] = __builtin_amdgcn_mfma_f32_16x16x32_bf16(af[i], bfr[j],
                                                              acc[i][j], 0, 0, 0);
    }
    BARRIER();   // all reads of this buffer done before it is re-staged
    cur ^= 1;
  }

#pragma unroll
  for (int i = 0; i < 4; ++i)
#pragma unroll
    for (int j = 0; j < NJ; ++j)
#pragma unroll
      for (int jr = 0; jr < 4; ++jr) {
        int row = row0 + wr * 64 + i * 16 + 4 * g + jr;
        int col = col0 + wc * (NJ * 16) + j * 16 + lq;
        float v = acc[i][j][jr];
        if (OUT_BF16)
          ((u16*)Cv)[(size_t)row * 1024 + col] = (u16)f2bf(v);
        else
          ((float*)Cv)[(size_t)row * 1024 + col] = v;
      }
}

// Fused Q/K/V projection: grid (32, 24); y>>3 selects the weight/output.
__global__ __launch_bounds__(256) void gemm_qkv_k(
    const u16* __restrict__ xb, const u16* __restrict__ Wqt,
    const u16* __restrict__ Wkt, const u16* __restrict__ Wvt,
    u16* __restrict__ Qr, u16* __restrict__ Kr, u16* __restrict__ Vr) {
  __shared__ __align__(16) char gsm[65536];   // 2 x (16K + 16K)
  const int which = blockIdx.y >> 3;
  const u16* Bt = which == 0 ? Wqt : (which == 1 ? Wkt : Wvt);
  u16* C = which == 0 ? Qr : (which == 1 ? Kr : Vr);
  gemm_body<1, 4>(gsm, xb, Bt, (void*)C, blockIdx.x * 128, (blockIdx.y & 7) * 128);
}

// Output projection: 128x64 tiles, grid (32, 16), fp32 out.
__global__ __launch_bounds__(256) void gemm_o_k(const u16* __restrict__ A,
                                                const u16* __restrict__ Bt,
                                                float* __restrict__ C) {
  __shared__ __align__(16) char gsm[49152];   // 2 x (16K + 8K)
  gemm_body<0, 2>(gsm, A, Bt, (void*)C, blockIdx.x * 128, blockIdx.y * 64);
}

// ---------------------------------------------------------------------------
// RoPE on K only (Q's RoPE is folded into attn's register prologue).
// [4096 m][1024 n] -> [bh][s][64]
// ---------------------------------------------------------------------------
__global__ __launch_bounds__(256) void ropeK_k(const u16* __restrict__ Kr,
                                               u16* __restrict__ Kb,
                                               const float* __restrict__ cosT,
                                               const float* __restrict__ sinT) {
  int i = blockIdx.x * 256 + threadIdx.x;
  size_t e = (size_t)i * 8;
  int m = (int)(e >> 10), n = (int)(e & 1023);
  int b = m >> 11, s = m & 2047, h = n >> 6, d = n & 63;
  float4 c4 = *(const float4*)(cosT + s * 32 + (d >> 1));
  float4 s4 = *(const float4*)(sinT + s * 32 + (d >> 1));
  bf16x8 v = *(const bf16x8*)(Kr + e);
  float cc[4] = {c4.x, c4.y, c4.z, c4.w}, sn[4] = {s4.x, s4.y, s4.z, s4.w};
  bf16x8 o;
#pragma unroll
  for (int j = 0; j < 4; ++j) {
    float re = bf2f(v[2 * j]), im = bf2f(v[2 * j + 1]);
    o[2 * j] = f2bf(re * cc[j] - im * sn[j]);
    o[2 * j + 1] = f2bf(re * sn[j] + im * cc[j]);
  }
  *(bf16x8*)(Kb + ((size_t)((b * 16 + h) * 2048 + s)) * 64 + d) = o;
}

// ---------------------------------------------------------------------------
// V transpose (P-fragment key permutation baked in) + fused column sums.
// Vr bf16 [m][1024] -> Vt [bh][64 d][2048 s'], s' = perm within 64-key tiles.
// Also: sumVp[sblk][bh][d] = sum of this block's 64 s-rows of V[.][d].
// ---------------------------------------------------------------------------
__global__ __launch_bounds__(256) void transV_k(const u16* __restrict__ Vr,
                                                u16* __restrict__ Vt,
                                                float* __restrict__ sumVp) {
  __shared__ u16 Ls[64 * 72];
  __shared__ float Sbuf[4][64];
  const int bh = blockIdx.y, s0 = blockIdx.x * 64;
  const int b = bh >> 4, h = bh & 15;
  const int t = threadIdx.x;
  const int sr = t >> 3, su = t & 7;
#pragma unroll
  for (int p = 0; p < 2; ++p) {
    int srow = sr + p * 32;
    bf16x8 v = *(const bf16x8*)(Vr + (size_t)(b * 2048 + s0 + srow) * 1024 + h * 64 + su * 8);
    *(bf16x8*)((char*)Ls + (srow * 72 + su * 8) * 2) = v;
  }
  __syncthreads();
  const int d = t >> 2, sc = (t & 3) * 16;   // keys sc..sc+15 of row d
  const int base = (sc & 32) + ((sc >> 4) & 1) * 4;
  u16* dst = Vt + ((size_t)bh * 64 + d) * 2048 + s0 + base;
#pragma unroll
  for (int q = 0; q < 4; ++q) {
    bf16x4 c;
#pragma unroll
    for (int jj = 0; jj < 4; ++jj) c[jj] = (short)Ls[(sc + q * 4 + jj) * 72 + d];
    *(bf16x4*)(dst + 8 * q) = c;
  }
  // fused column partial sums over this block's 64 rows
  const int d2 = t & 63, seg = t >> 6;
  float part = 0.f;
#pragma unroll
  for (int rr = 0; rr < 16; ++rr) part += bf2f((short)Ls[(seg * 16 + rr) * 72 + d2]);
  Sbuf[seg][d2] = part;
  __syncthreads();
  if (t < 64)
    sumVp[((size_t)blockIdx.x * 32 + bh) * 64 + t] =
        Sbuf[0][t] + Sbuf[1][t] + Sbuf[2][t] + Sbuf[3][t];
}

// ---------------------------------------------------------------------------
// Single-pass Taylor double-softmax flash attention, counted-vmcnt pipeline.
// out = (sumV + (sum exp2(s')*v)/l1) / 2049.
// Q read raw from Qr with RoPE applied in registers (amortized over 32 tiles);
// Q scale folds 0.125 and log2(e). K/V staged via global_load_lds dbuf with
// counted vmcnt + raw barriers (prefetch stays in flight across barrier).
// Note: attn writes Cb(=Qr) only into the exact region this block read.
// ---------------------------------------------------------------------------
__global__ __launch_bounds__(256) void attn_k(const u16* __restrict__ Qr,
                                              const u16* __restrict__ Kb,
                                              const u16* __restrict__ Vt,
                                              const float* __restrict__ sumVp,
                                              const float* __restrict__ cosT,
                                              const float* __restrict__ sinT,
                                              u16* __restrict__ Cb) {
  __shared__ __align__(16) char smem[33280];  // 2 x (K 8K | V 8K) | Lbuf 512B
  float* Lbuf = (float*)(smem + 32768);
  const int t = threadIdx.x;
  const int l = t & 63, w = t >> 6;
  const int lq = l & 15, g = l >> 4;
  const int qh = w & 1, kh = w >> 1;
  const int bh = blockIdx.y, q0 = blockIdx.x * 32;
  const int b = bh >> 4, h = bh & 15;

  // ---- Q load + in-register RoPE (scale = 0.125 * log2 e) ----
  const int sQ = q0 + qh * 16 + lq;
  const u16* qr = Qr + (size_t)(b * 2048 + sQ) * 1024 + h * 64;
  bf16x8 r0 = *(const bf16x8*)(qr + g * 8);
  bf16x8 r1 = *(const bf16x8*)(qr + 32 + g * 8);
  float4 c0 = *(const float4*)(cosT + sQ * 32 + g * 4);
  float4 n0 = *(const float4*)(sinT + sQ * 32 + g * 4);
  float4 c1 = *(const float4*)(cosT + sQ * 32 + 16 + g * 4);
  float4 n1 = *(const float4*)(sinT + sQ * 32 + 16 + g * 4);
  const float SC = 0.18033688011112042f;
  float cc0[4] = {c0.x, c0.y, c0.z, c0.w}, ss0[4] = {n0.x, n0.y, n0.z, n0.w};
  float cc1[4] = {c1.x, c1.y, c1.z, c1.w}, ss1[4] = {n1.x, n1.y, n1.z, n1.w};
  bf16x8 qf0, qf1;
#pragma unroll
  for (int j = 0; j < 4; ++j) {
    float re = bf2f(r0[2 * j]), im = bf2f(r0[2 * j + 1]);
    qf0[2 * j]     = f2bf((re * cc0[j] - im * ss0[j]) * SC);
    qf0[2 * j + 1] = f2bf((re * ss0[j] + im * cc0[j]) * SC);
    re = bf2f(r1[2 * j]); im = bf2f(r1[2 * j + 1]);
    qf1[2 * j]     = f2bf((re * cc1[j] - im * ss1[j]) * SC);
    qf1[2 * j + 1] = f2bf((re * ss1[j] + im * cc1[j]) * SC);
  }

  const int r8 = t >> 3;                       // staging row (0..31)
  const int c8 = (((t & 7) ^ (r8 & 7)) << 3);  // pre-swizzled col (elements)
  const size_t kbase = (size_t)bh * 2048 * 64;
  const size_t vbase = (size_t)bh * 64 * 2048;

  auto stage = [&](int cb, int j0) {
    char* dst = smem + cb * 16384 + w * 1024;
#pragma unroll
    for (int p = 0; p < 2; ++p) {
      gload16(Kb + kbase + (size_t)(j0 + r8 + 32 * p) * 64 + c8, dst + p * 4096);
      gload16(Vt + vbase + (size_t)(r8 + 32 * p) * 2048 + j0 + c8,
              dst + 8192 + p * 4096);
    }
  };

  float l1 = 0.0f;
  f32x4 accO[4] = {};

  stage(0, 0);
  int cur = 0;
  for (int j0 = 0; j0 < 2048; j0 += 64) {
    if (j0 + 64 < 2048) {
      stage(cur ^ 1, j0 + 64);
      WAITV(4);
    } else {
      WAITV(0);
    }
    BARRIER();
    __builtin_amdgcn_sched_barrier(0);
    const char* Kl = smem + cur * 16384;
    const char* Vl = Kl + 8192;
    // ---- scores (S^T = mfma(K, Q)) ----
    f32x4 sc[2] = {};
#pragma unroll
    for (int ks = 0; ks < 2; ++ks)
#pragma unroll
      for (int kt = 0; kt < 2; ++kt) {
        int r = kh * 32 + kt * 16 + lq, sA = ks * 4 + g;
        bf16x8 af = *(const bf16x8*)(Kl + r * 128 + ((sA ^ (r & 7)) << 4));
        sc[kt] = __builtin_amdgcn_mfma_f32_16x16x32_bf16(af, ks ? qf1 : qf0,
                                                         sc[kt], 0, 0, 0);
      }
    // ---- p = exp2(s'), l1 accumulate, pack bf16 ----
    float wv[2][4];
#pragma unroll
    for (int kt = 0; kt < 2; ++kt)
#pragma unroll
      for (int jr = 0; jr < 4; ++jr) {
        float e;
        asm("v_exp_f32 %0, %1" : "=v"(e) : "v"(sc[kt][jr]));
        wv[kt][jr] = e;
        l1 += e;
      }
    union { bf16x8 v; u32 uw[4]; } pb;
    asm("v_cvt_pk_bf16_f32 %0, %1, %2" : "=v"(pb.uw[0]) : "v"(wv[0][0]), "v"(wv[0][1]));
    asm("v_cvt_pk_bf16_f32 %0, %1, %2" : "=v"(pb.uw[1]) : "v"(wv[0][2]), "v"(wv[0][3]));
    asm("v_cvt_pk_bf16_f32 %0, %1, %2" : "=v"(pb.uw[2]) : "v"(wv[1][0]), "v"(wv[1][1]));
    asm("v_cvt_pk_bf16_f32 %0, %1, %2" : "=v"(pb.uw[3]) : "v"(wv[1][2]), "v"(wv[1][3]));
    // ---- PV accumulate ----
#pragma unroll
    for (int dt = 0; dt < 4; ++dt) {
      int dd = dt * 16 + lq;
      bf16x8 av = *(const bf16x8*)(Vl + dd * 128 +
                                   (((kh * 4 + g) ^ (dd & 7)) << 4));
      accO[dt] = __builtin_amdgcn_mfma_f32_16x16x32_bf16(av, pb.v, accO[dt], 0, 0, 0);
    }
    BARRIER();   // reads done before this buffer is re-staged
    cur ^= 1;
  }

  // ---- l1 merge: g-groups via shfl, kh pairs via LDS ----
  l1 += __shfl_xor(l1, 16);
  l1 += __shfl_xor(l1, 32);
  if (l < 16) Lbuf[w * 16 + l] = l1;
  __syncthreads();
  const float l1tot = Lbuf[w * 16 + lq] + Lbuf[(w ^ 2) * 16 + lq];
  const float rl1 = 1.0f / l1tot;

  // ---- accO merge (kh pairs) + transpose via LDS fp32 [32][65] ----
  float* Tb = (float*)smem;
  if (kh == 0) {
#pragma unroll
    for (int dt = 0; dt < 4; ++dt)
#pragma unroll
      for (int jr = 0; jr < 4; ++jr)
        Tb[(qh * 16 + lq) * 65 + dt * 16 + 4 * g + jr] = accO[dt][jr];
    if (l < 16) Lbuf[64 + qh * 16 + l] = rl1;
  }
  __syncthreads();
  if (kh == 1) {
#pragma unroll
    for (int dt = 0; dt < 4; ++dt)
#pragma unroll
      for (int jr = 0; jr < 4; ++jr)
        Tb[(qh * 16 + lq) * 65 + dt * 16 + 4 * g + jr] += accO[dt][jr];
  }
  __syncthreads();
  const int qq = t >> 3, dc = (t & 7) * 8;
  const float rq = Lbuf[64 + qq];
  f32x4 s0 = {}, s1 = {};
#pragma unroll 8
  for (int sl = 0; sl < 32; ++sl) {
    s0 += *(const f32x4*)(sumVp + ((size_t)sl * 32 + bh) * 64 + dc);
    s1 += *(const f32x4*)(sumVp + ((size_t)sl * 32 + bh) * 64 + dc + 4);
  }
  const float inv2049 = 1.0f / 2049.0f;
  bf16x8 o;
#pragma unroll
  for (int j = 0; j < 4; ++j) {
    o[j]     = f2bf((Tb[qq * 65 + dc + j] * rq + s0[j]) * inv2049);
    o[4 + j] = f2bf((Tb[qq * 65 + dc + 4 + j] * rq + s1[j]) * inv2049);
  }
  size_t obase = ((size_t)(b * 2048 + q0 + qq)) * 1024 + h * 64 + dc;
  *(bf16x8*)(Cb + obase) = o;
}

// ---------------------------------------------------------------------------
extern "C" void kernel_launch(void* const* d_in, const int* in_sizes, int n_in,
                              void* d_out, int out_size, void* d_ws, size_t ws_size,
                              hipStream_t stream) {
  const float* x = (const float*)d_in[0];
  const float* fcos = (const float*)d_in[1];
  const float* fsin = (const float*)d_in[2];
  const float* Wq = (const float*)d_in[3];
  const float* Wk = (const float*)d_in[4];
  const float* Wv = (const float*)d_in[5];
  const float* Wo = (const float*)d_in[6];
  float* out = (float*)d_out;

  char* wsp = (char*)d_ws;
  u16* xb  = (u16*)(wsp);                          // 8 MiB
  u16* Wqt = (u16*)(wsp + (8ull << 20));           // 2 MiB each
  u16* Wkt = (u16*)(wsp + (10ull << 20));
  u16* Wvt = (u16*)(wsp + (12ull << 20));
  u16* Wot = (u16*)(wsp + (14ull << 20));
  u16* Qr  = (u16*)(wsp + (16ull << 20));          // 8 MiB each
  u16* Kr  = (u16*)(wsp + (24ull << 20));
  u16* Vr  = (u16*)(wsp + (32ull << 20));
  u16* Kb  = (u16*)(wsp + (48ull << 20));
  u16* Vt  = (u16*)(wsp + (56ull << 20));
  float* sumVp = (float*)(wsp + (8ull << 20));     // reuse Wqt (dead after qkv)
  u16* Cb  = Qr;  // attn reads Qr region then overwrites the same region

  cast_k<<<2048, 256, 0, stream>>>(x, xb);
  dim3 gT(16, 16, 4);
  castT4_k<<<gT, 256, 0, stream>>>(Wq, Wk, Wv, Wo, Wqt, Wkt, Wvt, Wot);

  dim3 gQKV(32, 24);
  gemm_qkv_k<<<gQKV, 256, 0, stream>>>(xb, Wqt, Wkt, Wvt, Qr, Kr, Vr);

  ropeK_k<<<2048, 256, 0, stream>>>(Kr, Kb, fcos, fsin);
  dim3 gV(32, 32);
  transV_k<<<gV, 256, 0, stream>>>(Vr, Vt, sumVp);

  dim3 gA(64, 32);
  attn_k<<<gA, 256, 0, stream>>>(Qr, Kb, Vt, sumVp, fcos, fsin, Cb);

  dim3 gO(32, 16);
  gemm_o_k<<<gO, 256, 0, stream>>>(Cb, Wot, out);
}

// Round 9
// 208.076 us; speedup vs baseline: 1.0183x; 1.0183x over previous
//
#include <hip/hip_runtime.h>
#include <cstdint>

typedef unsigned short u16;
typedef unsigned int u32;
typedef __attribute__((ext_vector_type(8))) short bf16x8;
typedef __attribute__((ext_vector_type(4))) short bf16x4;
typedef __attribute__((ext_vector_type(4))) float f32x4;

__device__ __forceinline__ float bf2f(short h) {
  union { u32 u; float f; } x; x.u = ((u32)(u16)h) << 16; return x.f;
}
__device__ __forceinline__ short f2bf(float f) {
  union { float f; u32 u; } x; x.f = f;
  u32 r = x.u + 0x7fffu + ((x.u >> 16) & 1u);
  return (short)(u16)(r >> 16);
}

// async global->LDS, 16B per lane; LDS dest is wave-uniform base + lane*16
__device__ __forceinline__ void gload16(const void* g, void* l) {
  __builtin_amdgcn_global_load_lds(
      (const __attribute__((address_space(1))) u32*)g,
      (__attribute__((address_space(3))) u32*)l, 16, 0, 0);
}

// ---------------------------------------------------------------------------
// cast fp32 -> bf16, 8 elems/thread
// ---------------------------------------------------------------------------
__global__ __launch_bounds__(256) void cast_k(const float* __restrict__ in,
                                              u16* __restrict__ out) {
  int i = blockIdx.x * 256 + threadIdx.x;
  const float4* p = (const float4*)(in + (size_t)i * 8);
  float4 a = p[0], b = p[1];
  bf16x8 v;
  v[0] = f2bf(a.x); v[1] = f2bf(a.y); v[2] = f2bf(a.z); v[3] = f2bf(a.w);
  v[4] = f2bf(b.x); v[5] = f2bf(b.y); v[6] = f2bf(b.z); v[7] = f2bf(b.w);
  *(bf16x8*)(out + (size_t)i * 8) = v;
}

// ---------------------------------------------------------------------------
// cast+transpose all 4 weights: W fp32 [1024 k][1024 n] -> Wt bf16 [n][k]
// ---------------------------------------------------------------------------
__global__ __launch_bounds__(256) void castT4_k(
    const float* __restrict__ W0, const float* __restrict__ W1,
    const float* __restrict__ W2, const float* __restrict__ W3,
    u16* __restrict__ O0, u16* __restrict__ O1,
    u16* __restrict__ O2, u16* __restrict__ O3) {
  __shared__ u16 Ts[64 * 72];
  const int z = blockIdx.z;
  const float* in = z == 0 ? W0 : (z == 1 ? W1 : (z == 2 ? W2 : W3));
  u16* out = z == 0 ? O0 : (z == 1 ? O1 : (z == 2 ? O2 : O3));
  const int k0 = blockIdx.x * 64, n0 = blockIdx.y * 64;
  const int t = threadIdx.x;
  const int kr = t >> 4, nc = (t & 15) * 4;
#pragma unroll
  for (int p = 0; p < 4; ++p) {
    float4 v = *(const float4*)(in + (size_t)(k0 + kr + p * 16) * 1024 + n0 + nc);
    int kk = kr + p * 16;
    Ts[(nc + 0) * 72 + kk] = (u16)f2bf(v.x);
    Ts[(nc + 1) * 72 + kk] = (u16)f2bf(v.y);
    Ts[(nc + 2) * 72 + kk] = (u16)f2bf(v.z);
    Ts[(nc + 3) * 72 + kk] = (u16)f2bf(v.w);
  }
  __syncthreads();
  const int nr = t >> 2, kc = (t & 3) * 16;
  bf16x8 o0, o1;
#pragma unroll
  for (int j = 0; j < 8; ++j) {
    o0[j] = (short)Ts[nr * 72 + kc + j];
    o1[j] = (short)Ts[nr * 72 + kc + 8 + j];
  }
  *(bf16x8*)(out + (size_t)(n0 + nr) * 1024 + k0 + kc) = o0;
  *(bf16x8*)(out + (size_t)(n0 + nr) * 1024 + k0 + kc + 8) = o1;
}

// ---------------------------------------------------------------------------
// NT GEMM core, round-7-verified 2-phase pipeline (stage next; compute;
// __syncthreads — the end-of-iter drain only pays the prefetch remainder).
// BM=128, BN=NJ*32, BK=64, 4 waves; global_load_lds with pre-swizzled source.
// ---------------------------------------------------------------------------
template <int NJ>
__device__ __forceinline__ void gemm_core(char* gsm, const u16* __restrict__ A,
                                          const u16* __restrict__ Bt,
                                          int row0, int col0,
                                          f32x4 (&acc)[4][NJ]) {
  constexpr int SB = 16384 + NJ * 4096;   // per-buffer bytes (A 16K | B NJ*4K)
  const int t = threadIdx.x;
  const int l = t & 63, w = t >> 6;
  const int lq = l & 15, g = l >> 4;
  const int wr = w >> 1, wc = w & 1;
  const int r8 = t >> 3;                       // staging row (0..31)
  const int c8 = (((t & 7) ^ (r8 & 7)) << 3);  // pre-swizzled col (elements)

  auto stage = [&](int cb, int k0) {
    char* dst = gsm + cb * SB + w * 1024;
#pragma unroll
    for (int p = 0; p < 4; ++p)
      gload16(A + (size_t)(row0 + r8 + 32 * p) * 1024 + k0 + c8, dst + p * 4096);
#pragma unroll
    for (int p = 0; p < NJ; ++p)
      gload16(Bt + (size_t)(col0 + r8 + 32 * p) * 1024 + k0 + c8,
              dst + 16384 + p * 4096);
  };

  stage(0, 0);
  __syncthreads();
  int cur = 0;
  for (int k0 = 0; k0 < 1024; k0 += 64) {
    if (k0 + 64 < 1024) stage(cur ^ 1, k0 + 64);
    const char* Ab = gsm + cur * SB;
#pragma unroll
    for (int ks = 0; ks < 2; ++ks) {
      bf16x8 af[4], bfr[NJ];
      const int sA = ks * 4 + g;
#pragma unroll
      for (int i = 0; i < 4; ++i) {
        int ra = wr * 64 + i * 16 + lq;
        af[i] = *(const bf16x8*)(Ab + ra * 128 + ((sA ^ (ra & 7)) << 4));
      }
#pragma unroll
      for (int j = 0; j < NJ; ++j) {
        int rb = wc * (NJ * 16) + j * 16 + lq;
        bfr[j] = *(const bf16x8*)(Ab + 16384 + rb * 128 + ((sA ^ (rb & 7)) << 4));
      }
#pragma unroll
      for (int i = 0; i < 4; ++i)
#pragma unroll
        for (int j = 0; j < NJ; ++j)
          acc[i][j] = __builtin_amdgcn_mfma_f32_16x16x32_bf16(af[i], bfr[j],
                                                              acc[i][j], 0, 0, 0);
    }
    __syncthreads();
    cur ^= 1;
  }
}

// ---------------------------------------------------------------------------
// Fused Q/K/V projection with RoPE fused into the Q/K epilogues.
// grid (32, 24); which = y>>3 selects weight/output.
//   which==0 (Q): RoPE + scale (0.125*log2e), store (bh,s,64)
//   which==1 (K): RoPE,                      store (bh,s,64)
//   which==2 (V): raw bf16 [m][1024]
// RoPE pairing: lanes lq and lq^1 hold columns d and d^1 -> __shfl_xor(acc,1).
// Applied to fp32 accumulators (better than re-roping bf16-rounded values).
// ---------------------------------------------------------------------------
__global__ __launch_bounds__(256) void gemm_qkv_k(
    const u16* __restrict__ xb, const u16* __restrict__ Wqt,
    const u16* __restrict__ Wkt, const u16* __restrict__ Wvt,
    u16* __restrict__ Qb, u16* __restrict__ Kb, u16* __restrict__ Vr,
    const float* __restrict__ cosT, const float* __restrict__ sinT) {
  __shared__ __align__(16) char gsm[65536];   // 2 x (16K + 16K)
  const int which = blockIdx.y >> 3;
  const u16* Bt = which == 0 ? Wqt : (which == 1 ? Wkt : Wvt);
  const int row0 = blockIdx.x * 128, col0 = (blockIdx.y & 7) * 128;

  f32x4 acc[4][4] = {};
  gemm_core<4>(gsm, xb, Bt, row0, col0, acc);

  const int t = threadIdx.x;
  const int l = t & 63, w = t >> 6;
  const int lq = l & 15, g = l >> 4;
  const int wr = w >> 1, wc = w & 1;
  const float SC = 0.18033688011112042f;  // 0.125 * log2(e)

  if (which == 2) {
#pragma unroll
    for (int i = 0; i < 4; ++i)
#pragma unroll
      for (int j = 0; j < 4; ++j)
#pragma unroll
        for (int jr = 0; jr < 4; ++jr) {
          int row = row0 + wr * 64 + i * 16 + 4 * g + jr;
          int col = col0 + wc * 64 + j * 16 + lq;
          Vr[(size_t)row * 1024 + col] = (u16)f2bf(acc[i][j][jr]);
        }
  } else {
    u16* dstB = which == 0 ? Qb : Kb;
    const float sc = which == 0 ? SC : 1.0f;
#pragma unroll
    for (int i = 0; i < 4; ++i)
#pragma unroll
      for (int j = 0; j < 4; ++j)
#pragma unroll
        for (int jr = 0; jr < 4; ++jr) {
          int row = row0 + wr * 64 + i * 16 + 4 * g + jr;
          int col = col0 + wc * 64 + j * 16 + lq;
          int bb = row >> 11, ss = row & 2047;
          int hh = col >> 6, dd = col & 63;
          float v = acc[i][j][jr];
          float pv = __shfl_xor(v, 1);
          float c = cosT[ss * 32 + (dd >> 1)];
          float s = sinT[ss * 32 + (dd >> 1)];
          float o = (dd & 1) ? (pv * s + v * c) : (v * c - pv * s);
          dstB[(((size_t)bb * 16 + hh) * 2048 + ss) * 64 + dd] = (u16)f2bf(o * sc);
        }
  }
}

// Output projection: 128x64 tiles, grid (32, 16), fp32 out.
__global__ __launch_bounds__(256) void gemm_o_k(const u16* __restrict__ A,
                                                const u16* __restrict__ Bt,
                                                float* __restrict__ C) {
  __shared__ __align__(16) char gsm[49152];   // 2 x (16K + 8K)
  const int row0 = blockIdx.x * 128, col0 = blockIdx.y * 64;
  f32x4 acc[4][2] = {};
  gemm_core<2>(gsm, A, Bt, row0, col0, acc);
  const int t = threadIdx.x;
  const int l = t & 63, w = t >> 6;
  const int lq = l & 15, g = l >> 4;
  const int wr = w >> 1, wc = w & 1;
#pragma unroll
  for (int i = 0; i < 4; ++i)
#pragma unroll
    for (int j = 0; j < 2; ++j)
#pragma unroll
      for (int jr = 0; jr < 4; ++jr) {
        int row = row0 + wr * 64 + i * 16 + 4 * g + jr;
        int col = col0 + wc * 32 + j * 16 + lq;
        C[(size_t)row * 1024 + col] = acc[i][j][jr];
      }
}

// ---------------------------------------------------------------------------
// V transpose (P-fragment key permutation baked in) + fused column sums.
// Vr bf16 [m][1024] -> Vt [bh][64 d][2048 s'], s' = perm within 64-key tiles.
// Also: sumVp[sblk][bh][d] = sum of this block's 64 s-rows of V[.][d].
// ---------------------------------------------------------------------------
__global__ __launch_bounds__(256) void transV_k(const u16* __restrict__ Vr,
                                                u16* __restrict__ Vt,
                                                float* __restrict__ sumVp) {
  __shared__ u16 Ls[64 * 72];
  __shared__ float Sbuf[4][64];
  const int bh = blockIdx.y, s0 = blockIdx.x * 64;
  const int b = bh >> 4, h = bh & 15;
  const int t = threadIdx.x;
  const int sr = t >> 3, su = t & 7;
#pragma unroll
  for (int p = 0; p < 2; ++p) {
    int srow = sr + p * 32;
    bf16x8 v = *(const bf16x8*)(Vr + (size_t)(b * 2048 + s0 + srow) * 1024 + h * 64 + su * 8);
    *(bf16x8*)((char*)Ls + (srow * 72 + su * 8) * 2) = v;
  }
  __syncthreads();
  const int d = t >> 2, sc = (t & 3) * 16;   // keys sc..sc+15 of row d
  const int base = (sc & 32) + ((sc >> 4) & 1) * 4;
  u16* dst = Vt + ((size_t)bh * 64 + d) * 2048 + s0 + base;
#pragma unroll
  for (int q = 0; q < 4; ++q) {
    bf16x4 c;
#pragma unroll
    for (int jj = 0; jj < 4; ++jj) c[jj] = (short)Ls[(sc + q * 4 + jj) * 72 + d];
    *(bf16x4*)(dst + 8 * q) = c;
  }
  // fused column partial sums over this block's 64 rows
  const int d2 = t & 63, seg = t >> 6;
  float part = 0.f;
#pragma unroll
  for (int rr = 0; rr < 16; ++rr) part += bf2f((short)Ls[(seg * 16 + rr) * 72 + d2]);
  Sbuf[seg][d2] = part;
  __syncthreads();
  if (t < 64)
    sumVp[((size_t)blockIdx.x * 32 + bh) * 64 + t] =
        Sbuf[0][t] + Sbuf[1][t] + Sbuf[2][t] + Sbuf[3][t];
}

// ---------------------------------------------------------------------------
// Single-pass Taylor double-softmax flash attention (round-7 pipeline).
// out = (sumV + (sum exp2(s')*v)/l1) / 2049.
// Q/K arrive pre-RoPE'd (Q pre-scaled) in (bh,s,64). XCD-aware block swizzle:
// 2048 blocks = 8 XCDs x 256; each XCD's chunk spans only 4 bh values so its
// K/V working set (2 MB) is L2-resident.
// ---------------------------------------------------------------------------
__global__ __launch_bounds__(256) void attn_k(const u16* __restrict__ Qb,
                                              const u16* __restrict__ Kb,
                                              const u16* __restrict__ Vt,
                                              const float* __restrict__ sumVp,
                                              u16* __restrict__ Cb) {
  __shared__ __align__(16) char smem[33280];  // 2 x (K 8K | V 8K) | Lbuf 512B
  float* Lbuf = (float*)(smem + 32768);
  const int t = threadIdx.x;
  const int l = t & 63, w = t >> 6;
  const int lq = l & 15, g = l >> 4;
  const int qh = w & 1, kh = w >> 1;
  // XCD-aware swizzle (2048 % 8 == 0 -> bijective)
  const int bid = blockIdx.y * 64 + blockIdx.x;
  const int wg = (bid & 7) * 256 + (bid >> 3);
  const int bh = wg >> 6, q0 = (wg & 63) * 32;
  const int b = bh >> 4, h = bh & 15;

  const int sQ = q0 + qh * 16 + lq;
  const u16* qr = Qb + ((size_t)bh * 2048 + sQ) * 64;
  const bf16x8 qf0 = *(const bf16x8*)(qr + g * 8);
  const bf16x8 qf1 = *(const bf16x8*)(qr + 32 + g * 8);

  const int r8 = t >> 3;                       // staging row (0..31)
  const int c8 = (((t & 7) ^ (r8 & 7)) << 3);  // pre-swizzled col (elements)
  const size_t kbase = (size_t)bh * 2048 * 64;
  const size_t vbase = (size_t)bh * 64 * 2048;

  auto stage = [&](int cb, int j0) {
    char* dst = smem + cb * 16384 + w * 1024;
#pragma unroll
    for (int p = 0; p < 2; ++p) {
      gload16(Kb + kbase + (size_t)(j0 + r8 + 32 * p) * 64 + c8, dst + p * 4096);
      gload16(Vt + vbase + (size_t)(r8 + 32 * p) * 2048 + j0 + c8,
              dst + 8192 + p * 4096);
    }
  };

  float l1 = 0.0f;
  f32x4 accO[4] = {};

  stage(0, 0);
  __syncthreads();
  int cur = 0;
  for (int j0 = 0; j0 < 2048; j0 += 64) {
    if (j0 + 64 < 2048) stage(cur ^ 1, j0 + 64);
    const char* Kl = smem + cur * 16384;
    const char* Vl = Kl + 8192;
    // ---- scores (S^T = mfma(K, Q)) ----
    f32x4 sc[2] = {};
#pragma unroll
    for (int ks = 0; ks < 2; ++ks)
#pragma unroll
      for (int kt = 0; kt < 2; ++kt) {
        int r = kh * 32 + kt * 16 + lq, sA = ks * 4 + g;
        bf16x8 af = *(const bf16x8*)(Kl + r * 128 + ((sA ^ (r & 7)) << 4));
        sc[kt] = __builtin_amdgcn_mfma_f32_16x16x32_bf16(af, ks ? qf1 : qf0,
                                                         sc[kt], 0, 0, 0);
      }
    // ---- p = exp2(s'), l1 accumulate, pack bf16 ----
    float wv[2][4];
#pragma unroll
    for (int kt = 0; kt < 2; ++kt)
#pragma unroll
      for (int jr = 0; jr < 4; ++jr) {
        float e;
        asm("v_exp_f32 %0, %1" : "=v"(e) : "v"(sc[kt][jr]));
        wv[kt][jr] = e;
        l1 += e;
      }
    union { bf16x8 v; u32 uw[4]; } pb;
    asm("v_cvt_pk_bf16_f32 %0, %1, %2" : "=v"(pb.uw[0]) : "v"(wv[0][0]), "v"(wv[0][1]));
    asm("v_cvt_pk_bf16_f32 %0, %1, %2" : "=v"(pb.uw[1]) : "v"(wv[0][2]), "v"(wv[0][3]));
    asm("v_cvt_pk_bf16_f32 %0, %1, %2" : "=v"(pb.uw[2]) : "v"(wv[1][0]), "v"(wv[1][1]));
    asm("v_cvt_pk_bf16_f32 %0, %1, %2" : "=v"(pb.uw[3]) : "v"(wv[1][2]), "v"(wv[1][3]));
    // ---- PV accumulate ----
#pragma unroll
    for (int dt = 0; dt < 4; ++dt) {
      int dd = dt * 16 + lq;
      bf16x8 av = *(const bf16x8*)(Vl + dd * 128 +
                                   (((kh * 4 + g) ^ (dd & 7)) << 4));
      accO[dt] = __builtin_amdgcn_mfma_f32_16x16x32_bf16(av, pb.v, accO[dt], 0, 0, 0);
    }
    __syncthreads();
    cur ^= 1;
  }

  // ---- l1 merge: g-groups via shfl, kh pairs via LDS ----
  l1 += __shfl_xor(l1, 16);
  l1 += __shfl_xor(l1, 32);
  if (l < 16) Lbuf[w * 16 + l] = l1;
  __syncthreads();
  const float l1tot = Lbuf[w * 16 + lq] + Lbuf[(w ^ 2) * 16 + lq];
  const float rl1 = 1.0f / l1tot;

  // ---- accO merge (kh pairs) + transpose via LDS fp32 [32][65] ----
  float* Tb = (float*)smem;
  if (kh == 0) {
#pragma unroll
    for (int dt = 0; dt < 4; ++dt)
#pragma unroll
      for (int jr = 0; jr < 4; ++jr)
        Tb[(qh * 16 + lq) * 65 + dt * 16 + 4 * g + jr] = accO[dt][jr];
    if (l < 16) Lbuf[64 + qh * 16 + l] = rl1;
  }
  __syncthreads();
  if (kh == 1) {
#pragma unroll
    for (int dt = 0; dt < 4; ++dt)
#pragma unroll
      for (int jr = 0; jr < 4; ++jr)
        Tb[(qh * 16 + lq) * 65 + dt * 16 + 4 * g + jr] += accO[dt][jr];
  }
  __syncthreads();
  const int qq = t >> 3, dc = (t & 7) * 8;
  const float rq = Lbuf[64 + qq];
  f32x4 s0 = {}, s1 = {};
#pragma unroll 8
  for (int sl = 0; sl < 32; ++sl) {
    s0 += *(const f32x4*)(sumVp + ((size_t)sl * 32 + bh) * 64 + dc);
    s1 += *(const f32x4*)(sumVp + ((size_t)sl * 32 + bh) * 64 + dc + 4);
  }
  const float inv2049 = 1.0f / 2049.0f;
  bf16x8 o;
#pragma unroll
  for (int j = 0; j < 4; ++j) {
    o[j]     = f2bf((Tb[qq * 65 + dc + j] * rq + s0[j]) * inv2049);
    o[4 + j] = f2bf((Tb[qq * 65 + dc + 4 + j] * rq + s1[j]) * inv2049);
  }
  size_t obase = ((size_t)(b * 2048 + q0 + qq)) * 1024 + h * 64 + dc;
  *(bf16x8*)(Cb + obase) = o;
}

// ---------------------------------------------------------------------------
extern "C" void kernel_launch(void* const* d_in, const int* in_sizes, int n_in,
                              void* d_out, int out_size, void* d_ws, size_t ws_size,
                              hipStream_t stream) {
  const float* x = (const float*)d_in[0];
  const float* fcos = (const float*)d_in[1];
  const float* fsin = (const float*)d_in[2];
  const float* Wq = (const float*)d_in[3];
  const float* Wk = (const float*)d_in[4];
  const float* Wv = (const float*)d_in[5];
  const float* Wo = (const float*)d_in[6];
  float* out = (float*)d_out;

  char* wsp = (char*)d_ws;
  u16* xb  = (u16*)(wsp);                          // 8 MiB
  u16* Wqt = (u16*)(wsp + (8ull << 20));           // 2 MiB each
  u16* Wkt = (u16*)(wsp + (10ull << 20));
  u16* Wvt = (u16*)(wsp + (12ull << 20));
  u16* Wot = (u16*)(wsp + (14ull << 20));
  u16* Qb  = (u16*)(wsp + (16ull << 20));          // 8 MiB each
  u16* Kb  = (u16*)(wsp + (24ull << 20));
  u16* Vr  = (u16*)(wsp + (32ull << 20));
  u16* Vt  = (u16*)(wsp + (40ull << 20));
  u16* Cb  = (u16*)(wsp + (48ull << 20));
  float* sumVp = (float*)(wsp + (8ull << 20));     // reuse Wqt (dead after qkv)

  cast_k<<<2048, 256, 0, stream>>>(x, xb);
  dim3 gT(16, 16, 4);
  castT4_k<<<gT, 256, 0, stream>>>(Wq, Wk, Wv, Wo, Wqt, Wkt, Wvt, Wot);

  dim3 gQKV(32, 24);
  gemm_qkv_k<<<gQKV, 256, 0, stream>>>(xb, Wqt, Wkt, Wvt, Qb, Kb, Vr,
                                       fcos, fsin);

  dim3 gV(32, 32);
  transV_k<<<gV, 256, 0, stream>>>(Vr, Vt, sumVp);

  dim3 gA(64, 32);
  attn_k<<<gA, 256, 0, stream>>>(Qb, Kb, Vt, sumVp, Cb);

  dim3 gO(32, 16);
  gemm_o_k<<<gO, 256, 0, stream>>>(Cb, Wot, out);
}

// Round 10
// 188.750 us; speedup vs baseline: 1.1226x; 1.1024x over previous
//
#include <hip/hip_runtime.h>
#include <cstdint>

typedef unsigned short u16;
typedef unsigned int u32;
typedef __attribute__((ext_vector_type(8))) short bf16x8;
typedef __attribute__((ext_vector_type(4))) short bf16x4;
typedef __attribute__((ext_vector_type(4))) float f32x4;

__device__ __forceinline__ float bf2f(short h) {
  union { u32 u; float f; } x; x.u = ((u32)(u16)h) << 16; return x.f;
}
__device__ __forceinline__ short f2bf(float f) {
  union { float f; u32 u; } x; x.f = f;
  u32 r = x.u + 0x7fffu + ((x.u >> 16) & 1u);
  return (short)(u16)(r >> 16);
}

// async global->LDS, 16B per lane; LDS dest is wave-uniform base + lane*16
__device__ __forceinline__ void gload16(const void* g, void* l) {
  __builtin_amdgcn_global_load_lds(
      (const __attribute__((address_space(1))) u32*)g,
      (__attribute__((address_space(3))) u32*)l, 16, 0, 0);
}

// ---------------------------------------------------------------------------
// cast fp32 -> bf16, 8 elems/thread
// ---------------------------------------------------------------------------
__global__ __launch_bounds__(256) void cast_k(const float* __restrict__ in,
                                              u16* __restrict__ out) {
  int i = blockIdx.x * 256 + threadIdx.x;
  const float4* p = (const float4*)(in + (size_t)i * 8);
  float4 a = p[0], b = p[1];
  bf16x8 v;
  v[0] = f2bf(a.x); v[1] = f2bf(a.y); v[2] = f2bf(a.z); v[3] = f2bf(a.w);
  v[4] = f2bf(b.x); v[5] = f2bf(b.y); v[6] = f2bf(b.z); v[7] = f2bf(b.w);
  *(bf16x8*)(out + (size_t)i * 8) = v;
}

// ---------------------------------------------------------------------------
// cast+transpose all 4 weights: W fp32 [1024 k][1024 n] -> Wt bf16 [n][k]
// ---------------------------------------------------------------------------
__global__ __launch_bounds__(256) void castT4_k(
    const float* __restrict__ W0, const float* __restrict__ W1,
    const float* __restrict__ W2, const float* __restrict__ W3,
    u16* __restrict__ O0, u16* __restrict__ O1,
    u16* __restrict__ O2, u16* __restrict__ O3) {
  __shared__ u16 Ts[64 * 72];
  const int z = blockIdx.z;
  const float* in = z == 0 ? W0 : (z == 1 ? W1 : (z == 2 ? W2 : W3));
  u16* out = z == 0 ? O0 : (z == 1 ? O1 : (z == 2 ? O2 : O3));
  const int k0 = blockIdx.x * 64, n0 = blockIdx.y * 64;
  const int t = threadIdx.x;
  const int kr = t >> 4, nc = (t & 15) * 4;
#pragma unroll
  for (int p = 0; p < 4; ++p) {
    float4 v = *(const float4*)(in + (size_t)(k0 + kr + p * 16) * 1024 + n0 + nc);
    int kk = kr + p * 16;
    Ts[(nc + 0) * 72 + kk] = (u16)f2bf(v.x);
    Ts[(nc + 1) * 72 + kk] = (u16)f2bf(v.y);
    Ts[(nc + 2) * 72 + kk] = (u16)f2bf(v.z);
    Ts[(nc + 3) * 72 + kk] = (u16)f2bf(v.w);
  }
  __syncthreads();
  const int nr = t >> 2, kc = (t & 3) * 16;
  bf16x8 o0, o1;
#pragma unroll
  for (int j = 0; j < 8; ++j) {
    o0[j] = (short)Ts[nr * 72 + kc + j];
    o1[j] = (short)Ts[nr * 72 + kc + 8 + j];
  }
  *(bf16x8*)(out + (size_t)(n0 + nr) * 1024 + k0 + kc) = o0;
  *(bf16x8*)(out + (size_t)(n0 + nr) * 1024 + k0 + kc + 8) = o1;
}

// ---------------------------------------------------------------------------
// NT GEMM core, round-7-verified 2-phase pipeline (stage next; compute;
// __syncthreads — the end-of-iter drain only pays the prefetch remainder).
// BM=128, BN=NJ*32, BK=64, 4 waves; global_load_lds with pre-swizzled source.
// ---------------------------------------------------------------------------
template <int NJ>
__device__ __forceinline__ void gemm_core(char* gsm, const u16* __restrict__ A,
                                          const u16* __restrict__ Bt,
                                          int row0, int col0,
                                          f32x4 (&acc)[4][NJ]) {
  constexpr int SB = 16384 + NJ * 4096;   // per-buffer bytes (A 16K | B NJ*4K)
  const int t = threadIdx.x;
  const int l = t & 63, w = t >> 6;
  const int lq = l & 15, g = l >> 4;
  const int wr = w >> 1, wc = w & 1;
  const int r8 = t >> 3;                       // staging row (0..31)
  const int c8 = (((t & 7) ^ (r8 & 7)) << 3);  // pre-swizzled col (elements)

  auto stage = [&](int cb, int k0) {
    char* dst = gsm + cb * SB + w * 1024;
#pragma unroll
    for (int p = 0; p < 4; ++p)
      gload16(A + (size_t)(row0 + r8 + 32 * p) * 1024 + k0 + c8, dst + p * 4096);
#pragma unroll
    for (int p = 0; p < NJ; ++p)
      gload16(Bt + (size_t)(col0 + r8 + 32 * p) * 1024 + k0 + c8,
              dst + 16384 + p * 4096);
  };

  stage(0, 0);
  __syncthreads();
  int cur = 0;
  for (int k0 = 0; k0 < 1024; k0 += 64) {
    if (k0 + 64 < 1024) stage(cur ^ 1, k0 + 64);
    const char* Ab = gsm + cur * SB;
#pragma unroll
    for (int ks = 0; ks < 2; ++ks) {
      bf16x8 af[4], bfr[NJ];
      const int sA = ks * 4 + g;
#pragma unroll
      for (int i = 0; i < 4; ++i) {
        int ra = wr * 64 + i * 16 + lq;
        af[i] = *(const bf16x8*)(Ab + ra * 128 + ((sA ^ (ra & 7)) << 4));
      }
#pragma unroll
      for (int j = 0; j < NJ; ++j) {
        int rb = wc * (NJ * 16) + j * 16 + lq;
        bfr[j] = *(const bf16x8*)(Ab + 16384 + rb * 128 + ((sA ^ (rb & 7)) << 4));
      }
#pragma unroll
      for (int i = 0; i < 4; ++i)
#pragma unroll
        for (int j = 0; j < NJ; ++j)
          acc[i][j] = __builtin_amdgcn_mfma_f32_16x16x32_bf16(af[i], bfr[j],
                                                              acc[i][j], 0, 0, 0);
    }
    __syncthreads();
    cur ^= 1;
  }
}

// ---------------------------------------------------------------------------
// Fused Q/K/V projection with RoPE fused into the Q/K epilogues.
// grid (32, 24); which = y>>3 selects weight/output.
// ---------------------------------------------------------------------------
__global__ __launch_bounds__(256) void gemm_qkv_k(
    const u16* __restrict__ xb, const u16* __restrict__ Wqt,
    const u16* __restrict__ Wkt, const u16* __restrict__ Wvt,
    u16* __restrict__ Qb, u16* __restrict__ Kb, u16* __restrict__ Vr,
    const float* __restrict__ cosT, const float* __restrict__ sinT) {
  __shared__ __align__(16) char gsm[65536];   // 2 x (16K + 16K)
  const int which = blockIdx.y >> 3;
  const u16* Bt = which == 0 ? Wqt : (which == 1 ? Wkt : Wvt);
  const int row0 = blockIdx.x * 128, col0 = (blockIdx.y & 7) * 128;

  f32x4 acc[4][4] = {};
  gemm_core<4>(gsm, xb, Bt, row0, col0, acc);

  const int t = threadIdx.x;
  const int l = t & 63, w = t >> 6;
  const int lq = l & 15, g = l >> 4;
  const int wr = w >> 1, wc = w & 1;
  const float SC = 0.18033688011112042f;  // 0.125 * log2(e)

  if (which == 2) {
#pragma unroll
    for (int i = 0; i < 4; ++i)
#pragma unroll
      for (int j = 0; j < 4; ++j)
#pragma unroll
        for (int jr = 0; jr < 4; ++jr) {
          int row = row0 + wr * 64 + i * 16 + 4 * g + jr;
          int col = col0 + wc * 64 + j * 16 + lq;
          Vr[(size_t)row * 1024 + col] = (u16)f2bf(acc[i][j][jr]);
        }
  } else {
    u16* dstB = which == 0 ? Qb : Kb;
    const float sc = which == 0 ? SC : 1.0f;
#pragma unroll
    for (int i = 0; i < 4; ++i)
#pragma unroll
      for (int j = 0; j < 4; ++j)
#pragma unroll
        for (int jr = 0; jr < 4; ++jr) {
          int row = row0 + wr * 64 + i * 16 + 4 * g + jr;
          int col = col0 + wc * 64 + j * 16 + lq;
          int bb = row >> 11, ss = row & 2047;
          int hh = col >> 6, dd = col & 63;
          float v = acc[i][j][jr];
          float pv = __shfl_xor(v, 1);
          float c = cosT[ss * 32 + (dd >> 1)];
          float s = sinT[ss * 32 + (dd >> 1)];
          float o = (dd & 1) ? (pv * s + v * c) : (v * c - pv * s);
          dstB[(((size_t)bb * 16 + hh) * 2048 + ss) * 64 + dd] = (u16)f2bf(o * sc);
        }
  }
}

// Output projection: 128x64 tiles, grid (32, 16), fp32 out.
__global__ __launch_bounds__(256) void gemm_o_k(const u16* __restrict__ A,
                                                const u16* __restrict__ Bt,
                                                float* __restrict__ C) {
  __shared__ __align__(16) char gsm[49152];   // 2 x (16K + 8K)
  const int row0 = blockIdx.x * 128, col0 = blockIdx.y * 64;
  f32x4 acc[4][2] = {};
  gemm_core<2>(gsm, A, Bt, row0, col0, acc);
  const int t = threadIdx.x;
  const int l = t & 63, w = t >> 6;
  const int lq = l & 15, g = l >> 4;
  const int wr = w >> 1, wc = w & 1;
#pragma unroll
  for (int i = 0; i < 4; ++i)
#pragma unroll
    for (int j = 0; j < 2; ++j)
#pragma unroll
      for (int jr = 0; jr < 4; ++jr) {
        int row = row0 + wr * 64 + i * 16 + 4 * g + jr;
        int col = col0 + wc * 32 + j * 16 + lq;
        C[(size_t)row * 1024 + col] = acc[i][j][jr];
      }
}

// ---------------------------------------------------------------------------
// V transpose (P-fragment key permutation baked in) + fused column sums.
// ---------------------------------------------------------------------------
__global__ __launch_bounds__(256) void transV_k(const u16* __restrict__ Vr,
                                                u16* __restrict__ Vt,
                                                float* __restrict__ sumVp) {
  __shared__ u16 Ls[64 * 72];
  __shared__ float Sbuf[4][64];
  const int bh = blockIdx.y, s0 = blockIdx.x * 64;
  const int b = bh >> 4, h = bh & 15;
  const int t = threadIdx.x;
  const int sr = t >> 3, su = t & 7;
#pragma unroll
  for (int p = 0; p < 2; ++p) {
    int srow = sr + p * 32;
    bf16x8 v = *(const bf16x8*)(Vr + (size_t)(b * 2048 + s0 + srow) * 1024 + h * 64 + su * 8);
    *(bf16x8*)((char*)Ls + (srow * 72 + su * 8) * 2) = v;
  }
  __syncthreads();
  const int d = t >> 2, sc = (t & 3) * 16;   // keys sc..sc+15 of row d
  const int base = (sc & 32) + ((sc >> 4) & 1) * 4;
  u16* dst = Vt + ((size_t)bh * 64 + d) * 2048 + s0 + base;
#pragma unroll
  for (int q = 0; q < 4; ++q) {
    bf16x4 c;
#pragma unroll
    for (int jj = 0; jj < 4; ++jj) c[jj] = (short)Ls[(sc + q * 4 + jj) * 72 + d];
    *(bf16x4*)(dst + 8 * q) = c;
  }
  const int d2 = t & 63, seg = t >> 6;
  float part = 0.f;
#pragma unroll
  for (int rr = 0; rr < 16; ++rr) part += bf2f((short)Ls[(seg * 16 + rr) * 72 + d2]);
  Sbuf[seg][d2] = part;
  __syncthreads();
  if (t < 64)
    sumVp[((size_t)blockIdx.x * 32 + bh) * 64 + t] =
        Sbuf[0][t] + Sbuf[1][t] + Sbuf[2][t] + Sbuf[3][t];
}

// ---------------------------------------------------------------------------
// Single-pass Taylor double-softmax flash attention.
// NEW structure: 64 q-rows/block, 4 waves, EACH WAVE owns 16 q-rows x all 64
// keys of the tile (no kh split): per staged tile the block runs 64 MFMAs
// (2x the old ratio), and no cross-wave accO/l1 merge is needed.
// PV key mapping (verified round 4): keys 0..31 -> pbA + V slot g;
// keys 32..63 -> pbB + V slot 4+g (the old kh=0/kh=1 roles in one wave).
// out = (sumV + (sum exp2(s')*v)/l1) / 2049.
// ---------------------------------------------------------------------------
__global__ __launch_bounds__(256) void attn_k(const u16* __restrict__ Qb,
                                              const u16* __restrict__ Kb,
                                              const u16* __restrict__ Vt,
                                              const float* __restrict__ sumVp,
                                              u16* __restrict__ Cb) {
  __shared__ __align__(16) char smem[33280];  // 2 x (K 8K | V 8K) | Svb 512B
  float* Svb = (float*)(smem + 32768);        // [0:64) precomputed sumV
  const int t = threadIdx.x;
  const int l = t & 63, w = t >> 6;
  const int lq = l & 15, g = l >> 4;
  const int bh = blockIdx.y, q0 = blockIdx.x * 64;
  const int b = bh >> 4, h = bh & 15;

  const int sQ = q0 + w * 16 + lq;
  const u16* qr = Qb + ((size_t)bh * 2048 + sQ) * 64;
  const bf16x8 qf0 = *(const bf16x8*)(qr + g * 8);
  const bf16x8 qf1 = *(const bf16x8*)(qr + 32 + g * 8);

  const int r8 = t >> 3;                       // staging row (0..31)
  const int c8 = (((t & 7) ^ (r8 & 7)) << 3);  // pre-swizzled col (elements)
  const size_t kbase = (size_t)bh * 2048 * 64;
  const size_t vbase = (size_t)bh * 64 * 2048;

  auto stage = [&](int cb, int j0) {
    char* dst = smem + cb * 16384 + w * 1024;
#pragma unroll
    for (int p = 0; p < 2; ++p) {
      gload16(Kb + kbase + (size_t)(j0 + r8 + 32 * p) * 64 + c8, dst + p * 4096);
      gload16(Vt + vbase + (size_t)(r8 + 32 * p) * 2048 + j0 + c8,
              dst + 8192 + p * 4096);
    }
  };

  stage(0, 0);
  // precompute block-wide sumV (64 d-values) while loads fly
  if (t < 64) {
    float sv = 0.f;
#pragma unroll 8
    for (int sl = 0; sl < 32; ++sl) sv += sumVp[((size_t)sl * 32 + bh) * 64 + t];
    Svb[t] = sv;
  }
  __syncthreads();

  float l1 = 0.0f;
  f32x4 accO[4] = {};
  int cur = 0;
  for (int j0 = 0; j0 < 2048; j0 += 64) {
    if (j0 + 64 < 2048) stage(cur ^ 1, j0 + 64);
    const char* Kl = smem + cur * 16384;
    const char* Vl = Kl + 8192;
    // ---- scores: 4 key-groups x 2 k-halves (wave covers all 64 keys) ----
    f32x4 sc[4] = {};
#pragma unroll
    for (int ks = 0; ks < 2; ++ks)
#pragma unroll
      for (int kt = 0; kt < 4; ++kt) {
        int r = kt * 16 + lq, sA = ks * 4 + g;
        bf16x8 af = *(const bf16x8*)(Kl + r * 128 + ((sA ^ (r & 7)) << 4));
        sc[kt] = __builtin_amdgcn_mfma_f32_16x16x32_bf16(af, ks ? qf1 : qf0,
                                                         sc[kt], 0, 0, 0);
      }
    // ---- p = exp2(s'), l1 accumulate ----
    float wv[4][4];
#pragma unroll
    for (int kt = 0; kt < 4; ++kt)
#pragma unroll
      for (int jr = 0; jr < 4; ++jr) {
        float e;
        asm("v_exp_f32 %0, %1" : "=v"(e) : "v"(sc[kt][jr]));
        wv[kt][jr] = e;
        l1 += e;
      }
    // ---- pack two P fragments (keys 0..31 -> pbA, 32..63 -> pbB) ----
    union { bf16x8 v; u32 uw[4]; } pbA, pbB;
    asm("v_cvt_pk_bf16_f32 %0, %1, %2" : "=v"(pbA.uw[0]) : "v"(wv[0][0]), "v"(wv[0][1]));
    asm("v_cvt_pk_bf16_f32 %0, %1, %2" : "=v"(pbA.uw[1]) : "v"(wv[0][2]), "v"(wv[0][3]));
    asm("v_cvt_pk_bf16_f32 %0, %1, %2" : "=v"(pbA.uw[2]) : "v"(wv[1][0]), "v"(wv[1][1]));
    asm("v_cvt_pk_bf16_f32 %0, %1, %2" : "=v"(pbA.uw[3]) : "v"(wv[1][2]), "v"(wv[1][3]));
    asm("v_cvt_pk_bf16_f32 %0, %1, %2" : "=v"(pbB.uw[0]) : "v"(wv[2][0]), "v"(wv[2][1]));
    asm("v_cvt_pk_bf16_f32 %0, %1, %2" : "=v"(pbB.uw[1]) : "v"(wv[2][2]), "v"(wv[2][3]));
    asm("v_cvt_pk_bf16_f32 %0, %1, %2" : "=v"(pbB.uw[2]) : "v"(wv[3][0]), "v"(wv[3][1]));
    asm("v_cvt_pk_bf16_f32 %0, %1, %2" : "=v"(pbB.uw[3]) : "v"(wv[3][2]), "v"(wv[3][3]));
    // ---- PV accumulate (two 32-key MFMAs per d-group) ----
#pragma unroll
    for (int dt = 0; dt < 4; ++dt) {
      int dd = dt * 16 + lq;
      bf16x8 avA = *(const bf16x8*)(Vl + dd * 128 + ((g ^ (dd & 7)) << 4));
      accO[dt] = __builtin_amdgcn_mfma_f32_16x16x32_bf16(avA, pbA.v, accO[dt], 0, 0, 0);
      bf16x8 avB = *(const bf16x8*)(Vl + dd * 128 + (((4 + g) ^ (dd & 7)) << 4));
      accO[dt] = __builtin_amdgcn_mfma_f32_16x16x32_bf16(avB, pbB.v, accO[dt], 0, 0, 0);
    }
    __syncthreads();
    cur ^= 1;
  }

  // ---- l1 merge across g-groups only (wave owns all keys) ----
  l1 += __shfl_xor(l1, 16);
  l1 += __shfl_xor(l1, 32);
  const float rl1 = 1.0f / l1;

  // ---- transpose via LDS fp32 [64][65], rl1 folded at write ----
  float* Tb = (float*)smem;
#pragma unroll
  for (int dt = 0; dt < 4; ++dt)
#pragma unroll
    for (int jr = 0; jr < 4; ++jr)
      Tb[(w * 16 + lq) * 65 + dt * 16 + 4 * g + jr] = accO[dt][jr] * rl1;
  __syncthreads();
  const int qq = t >> 2, dc = (t & 3) * 16;
  const float inv2049 = 1.0f / 2049.0f;
  bf16x8 o0, o1;
#pragma unroll
  for (int j = 0; j < 8; ++j) {
    o0[j] = f2bf((Tb[qq * 65 + dc + j] + Svb[dc + j]) * inv2049);
    o1[j] = f2bf((Tb[qq * 65 + dc + 8 + j] + Svb[dc + 8 + j]) * inv2049);
  }
  size_t obase = ((size_t)(b * 2048 + q0 + qq)) * 1024 + h * 64 + dc;
  *(bf16x8*)(Cb + obase) = o0;
  *(bf16x8*)(Cb + obase + 8) = o1;
}

// ---------------------------------------------------------------------------
extern "C" void kernel_launch(void* const* d_in, const int* in_sizes, int n_in,
                              void* d_out, int out_size, void* d_ws, size_t ws_size,
                              hipStream_t stream) {
  const float* x = (const float*)d_in[0];
  const float* fcos = (const float*)d_in[1];
  const float* fsin = (const float*)d_in[2];
  const float* Wq = (const float*)d_in[3];
  const float* Wk = (const float*)d_in[4];
  const float* Wv = (const float*)d_in[5];
  const float* Wo = (const float*)d_in[6];
  float* out = (float*)d_out;

  char* wsp = (char*)d_ws;
  u16* xb  = (u16*)(wsp);                          // 8 MiB
  u16* Wqt = (u16*)(wsp + (8ull << 20));           // 2 MiB each
  u16* Wkt = (u16*)(wsp + (10ull << 20));
  u16* Wvt = (u16*)(wsp + (12ull << 20));
  u16* Wot = (u16*)(wsp + (14ull << 20));
  u16* Qb  = (u16*)(wsp + (16ull << 20));          // 8 MiB each
  u16* Kb  = (u16*)(wsp + (24ull << 20));
  u16* Vr  = (u16*)(wsp + (32ull << 20));
  u16* Vt  = (u16*)(wsp + (40ull << 20));
  u16* Cb  = (u16*)(wsp + (48ull << 20));
  float* sumVp = (float*)(wsp + (8ull << 20));     // reuse Wqt (dead after qkv)

  cast_k<<<2048, 256, 0, stream>>>(x, xb);
  dim3 gT(16, 16, 4);
  castT4_k<<<gT, 256, 0, stream>>>(Wq, Wk, Wv, Wo, Wqt, Wkt, Wvt, Wot);

  dim3 gQKV(32, 24);
  gemm_qkv_k<<<gQKV, 256, 0, stream>>>(xb, Wqt, Wkt, Wvt, Qb, Kb, Vr,
                                       fcos, fsin);

  dim3 gV(32, 32);
  transV_k<<<gV, 256, 0, stream>>>(Vr, Vt, sumVp);

  dim3 gA(32, 32);
  attn_k<<<gA, 256, 0, stream>>>(Qb, Kb, Vt, sumVp, Cb);

  dim3 gO(32, 16);
  gemm_o_k<<<gO, 256, 0, stream>>>(Cb, Wot, out);
}